// Round 7
// baseline (3844.231 us; speedup 1.0000x reference)
//
#include <hip/hip_runtime.h>

// ---------------- problem constants ----------------
#define TPB   256
#define NWG   256
#define SEQL  200
#define BATCH 64
#define EDIM  300
#define HDIM  512
#define ODIM  5
#define NROW  (4*HDIM)   // 2048 gate rows

// ---------------- group decomposition ----------------
#define GROUPS 8      // independent batch groups (group = blockIdx & 7)
#define GCUS   32     // CUs per group (j = blockIdx >> 3)
#define GB     8      // batch rows per group
#define UNITS  16     // h units per CU
#define ROWS   64     // gate rows per CU (= UNITS * 4 gates)
#define KSLC   32     // k per kh slice (16 slices)

// ---------------- persist-kernel LDS layout (word offsets) ----------------
// [0..4096)      h tile [512 k][8 b], half-XOR swizzled: phys = 8k + 4*(half ^ ((k>>5)&1)) + (b&3)
// [4096..12864)  ex[64 r][8 b][17]  (r stride 137, b stride 17)
// [12864..15264) embT[300][8] (fallback only)
#define H_WORDS  4096
#define EX_OFF   4096
#define EX_RSTR  137
#define EX_BSTR  17
#define EMB_OFF  (EX_OFF + ROWS*EX_RSTR)     // 12864
#define LDS_WORDS (EMB_OFF + EDIM*GB)        // 15264 words = 61056 B actually used
#define LDS_BYTES 83968                      // padded: 2*83968 > 160KiB -> 1 wg/CU

#define HSLOT_WORDS (GROUPS * H_WORDS)       // 32768 floats = 128 KiB per rotation slot
#define HSLOT_BYTES (HSLOT_WORDS * 4)

// ---------------- precompute-kernel LDS ----------------
#define ESTR 308
#define PRE_LDS_BYTES (BATCH * ESTR * 4)     // 78848 B

#define GATES_FLOATS ((size_t)SEQL * NROW * BATCH)   // 104.9 MB

__device__ __forceinline__ float fast_sigmoid(float x) {
    return 1.0f / (1.0f + __expf(-x));
}
__device__ __forceinline__ float fast_tanh(float x) {
    return 2.0f / (1.0f + __expf(-2.0f * x)) - 1.0f;
}

// ============================================================================
// Precompute: gates[s][row][b] = (x_s @ W_ih^T)[b][row]   (no bias)
// ============================================================================
extern "C" __global__ void __launch_bounds__(256, 1)
lstm_pre(const int* __restrict__ x, const float* __restrict__ emb,
         const float* __restrict__ W_ih, float* __restrict__ gates)
{
    extern __shared__ float embs[];
    const int tid = threadIdx.x;
    const int s   = blockIdx.x >> 3;
    const int rb  = blockIdx.x & 7;

    for (int i = tid; i < BATCH * 75; i += 256) {
        int b = i / 75, jj = i - b * 75;
        int row = x[b * SEQL + s];
        float4 v = ((const float4*)(emb + (size_t)row * EDIM))[jj];
        *(float4*)&embs[b * ESTR + 4 * jj] = v;
    }
    __syncthreads();

    const int bi = tid >> 5;
    const int ri = tid & 31;
    const int row0 = rb * 256 + ri * 8;
    const float* wp = W_ih + (size_t)row0 * EDIM;

    float acc[8][8];
#pragma unroll
    for (int a = 0; a < 8; a++)
#pragma unroll
        for (int b = 0; b < 8; b++) acc[a][b] = 0.0f;

    for (int t2 = 0; t2 < 75; t2++) {
        float4 w[8], e[8];
#pragma unroll
        for (int rr = 0; rr < 8; rr++)
            w[rr] = *(const float4*)(wp + rr * EDIM + 4 * t2);
#pragma unroll
        for (int bb = 0; bb < 8; bb++)
            e[bb] = *(const float4*)&embs[(bi * 8 + bb) * ESTR + 4 * t2];
#pragma unroll
        for (int rr = 0; rr < 8; rr++)
#pragma unroll
            for (int bb = 0; bb < 8; bb++) {
                acc[rr][bb] = fmaf(w[rr].x, e[bb].x, acc[rr][bb]);
                acc[rr][bb] = fmaf(w[rr].y, e[bb].y, acc[rr][bb]);
                acc[rr][bb] = fmaf(w[rr].z, e[bb].z, acc[rr][bb]);
                acc[rr][bb] = fmaf(w[rr].w, e[bb].w, acc[rr][bb]);
            }
    }
#pragma unroll
    for (int rr = 0; rr < 8; rr++) {
        float* dst = gates + ((size_t)s * NROW + row0 + rr) * BATCH + bi * 8;
        *(float4*)dst       = make_float4(acc[rr][0], acc[rr][1], acc[rr][2], acc[rr][3]);
        *(float4*)(dst + 4) = make_float4(acc[rr][4], acc[rr][5], acc[rr][6], acc[rr][7]);
    }
}

// ============================================================================
// Persistent LSTM, 8 independent batch-groups of 32 CUs.
// Group g = blockIdx&7 owns batch rows 8g..8g+7; CU j = blockIdx>>3 owns
// h-units 16j..16j+15 (x4 gates = 64 gate rows). Per-step exchange: 16 KB
// within the group only. Thread roles: rq = tid&15 (4 rows), kh = tid>>4
// (32-k slice). W_hh slice in 128 VGPRs; h tile in LDS (2-way reads = free).
// ============================================================================
extern "C" __global__ void __launch_bounds__(TPB, 1)
lstm_persist(const int* __restrict__ x, const float* __restrict__ emb,
             const float* __restrict__ W_ih, const float* __restrict__ W_hh,
             const float* __restrict__ b_ih, const float* __restrict__ b_hh,
             const float* __restrict__ gates,   // may be null
             float* __restrict__ hrot,          // rot_n slots of [8 grp][512][8]
             int rot_n,
             unsigned int* __restrict__ flags)  // [256] = [grp][32], memset 0
{
    extern __shared__ float lds[];
    const int tid = threadIdx.x;
    const int g   = blockIdx.x & 7;
    const int j   = blockIdx.x >> 3;
    const bool pre = (gates != nullptr);

    const int rq = tid & 15;      // rows 4rq..4rq+3 (r = gate*16+u)
    const int kh = tid >> 4;      // k in [32kh, 32kh+32)

    // ---- W_hh slice -> 128 VGPRs ----
    float4 w4[4][8];
#pragma unroll
    for (int p = 0; p < 4; p++) {
        const int r = 4 * rq + p;
        const size_t R = (size_t)((r >> 4) * HDIM + UNITS * j + (r & 15));
        const float* wp = W_hh + R * HDIM + KSLC * kh;
#pragma unroll
        for (int kq = 0; kq < 8; kq++) w4[p][kq] = *(const float4*)(wp + 4 * kq);
    }

    // cell role: tid<128 owns (u = tid>>3, b = tid&7)
    const int cu = tid >> 3;      // valid when tid<128
    const int cbb = tid & 7;
    float bias4[4];
#pragma unroll
    for (int gt = 0; gt < 4; gt++) {
        int R = gt * HDIM + UNITS * j + (cu & 15);
        bias4[gt] = b_ih[R] + b_hh[R];
    }
    float c_reg = 0.0f;

    const int sw = 4 * (kh & 1);  // pass-B half-XOR select

    int rbuf = 0, wbuf = 1;
    unsigned int* const myflags = flags + 32 * g;
    __syncthreads();

    for (int s = 0; s < SEQL; s++) {
        // ---- (0) prefetch input-projection gates (latency hides under poll) ----
        float gp[4] = {0.f, 0.f, 0.f, 0.f};
        if (pre && tid < 128) {
#pragma unroll
            for (int gt = 0; gt < 4; gt++)
                gp[gt] = gates[((size_t)s * NROW + gt * HDIM + UNITS * j + cu) * BATCH + GB * g + cbb];
        }

        float acc[4][8];
#pragma unroll
        for (int p = 0; p < 4; p++)
#pragma unroll
            for (int b = 0; b < 8; b++) acc[p][b] = 0.f;

        // ---- (1) fallback pass A (inline, before poll; pre-path skips) ----
        if (!pre) {
            for (int i = tid; i < EDIM * GB; i += TPB) {
                int e = i >> 3, b = i & 7;
                int row = x[(GB * g + b) * SEQL + s];
                lds[EMB_OFF + e * 8 + b] = emb[(size_t)row * EDIM + e];
            }
            __syncthreads();
            if (kh < 15) {
                for (int e = 20 * kh; e < 20 * kh + 20; e++) {
                    float4 e0 = *(const float4*)&lds[EMB_OFF + e * 8];
                    float4 e1 = *(const float4*)&lds[EMB_OFF + e * 8 + 4];
#pragma unroll
                    for (int p = 0; p < 4; p++) {
                        const int r = 4 * rq + p;
                        const size_t R = (size_t)((r >> 4) * HDIM + UNITS * j + (r & 15));
                        float wc = W_ih[R * EDIM + e];
                        acc[p][0] = fmaf(wc, e0.x, acc[p][0]);
                        acc[p][1] = fmaf(wc, e0.y, acc[p][1]);
                        acc[p][2] = fmaf(wc, e0.z, acc[p][2]);
                        acc[p][3] = fmaf(wc, e0.w, acc[p][3]);
                        acc[p][4] = fmaf(wc, e1.x, acc[p][4]);
                        acc[p][5] = fmaf(wc, e1.y, acc[p][5]);
                        acc[p][6] = fmaf(wc, e1.z, acc[p][6]);
                        acc[p][7] = fmaf(wc, e1.w, acc[p][7]);
                    }
                }
            }
        }

        if (s) {
            // ---- (2) group barrier: 32 flags, one per lane ----
            if (tid < 32) {
                const unsigned tgt = (unsigned)s;
                while (__hip_atomic_load(myflags + tid, __ATOMIC_RELAXED,
                                         __HIP_MEMORY_SCOPE_AGENT) < tgt)
                    __builtin_amdgcn_s_sleep(1);
                __builtin_amdgcn_fence(__ATOMIC_ACQUIRE, "agent");  // L1+L2 inv
            }
            __syncthreads();

            // ---- (3) stage h tile (16 KB): 4 loads + 4 swizzled LDS writes ----
            const float* hs = hrot + (size_t)rbuf * HSLOT_WORDS + (size_t)g * H_WORDS;
            float4 hv[4];
#pragma unroll
            for (int u = 0; u < 4; u++)
                hv[u] = *(const float4*)(hs + 4 * (tid + 256 * u));
#pragma unroll
            for (int u = 0; u < 4; u++) {
                const int blk = tid + 256 * u;
                const int k = blk >> 1, hf = blk & 1;
                const int phys = 8 * k + 4 * (hf ^ ((k >> 5) & 1));
                *(float4*)&lds[phys] = hv[u];
            }
            __syncthreads();

            // ---- (4) pass B: W_hh regs x h LDS (2-way reads = free) ----
#pragma unroll 8
            for (int kidx = 0; kidx < KSLC; kidx++) {
                const int kb = 256 * kh + 8 * kidx;
                float4 h0 = *(const float4*)&lds[kb + sw];        // b 0-3
                float4 h1 = *(const float4*)&lds[kb + (4 - sw)];  // b 4-7
#pragma unroll
                for (int p = 0; p < 4; p++) {
                    const float4 wv = w4[p][kidx >> 2];
                    const float wc = (kidx & 3) == 0 ? wv.x : (kidx & 3) == 1 ? wv.y
                                   : (kidx & 3) == 2 ? wv.z : wv.w;
                    acc[p][0] = fmaf(wc, h0.x, acc[p][0]);
                    acc[p][1] = fmaf(wc, h0.y, acc[p][1]);
                    acc[p][2] = fmaf(wc, h0.z, acc[p][2]);
                    acc[p][3] = fmaf(wc, h0.w, acc[p][3]);
                    acc[p][4] = fmaf(wc, h1.x, acc[p][4]);
                    acc[p][5] = fmaf(wc, h1.y, acc[p][5]);
                    acc[p][6] = fmaf(wc, h1.z, acc[p][6]);
                    acc[p][7] = fmaf(wc, h1.w, acc[p][7]);
                }
            }
        }
        __syncthreads();   // h-tile readers done; ex region reusable

        // ---- (5) exchange k-partials: ex[r][b][kh], ~2-way banks ----
#pragma unroll
        for (int p = 0; p < 4; p++) {
            const int base = EX_OFF + (4 * rq + p) * EX_RSTR + kh;
#pragma unroll
            for (int b = 0; b < 8; b++)
                lds[base + b * EX_BSTR] = acc[p][b];
        }
        __syncthreads();

        // ---- (6) cell update (tid<128 owns (u, b)) ----
        if (tid < 128) {
            float gs[4];
#pragma unroll
            for (int gt = 0; gt < 4; gt++) {
                float sum = bias4[gt] + gp[gt];
                const int base = EX_OFF + (gt * 16 + cu) * EX_RSTR + cbb * EX_BSTR;
#pragma unroll
                for (int kk = 0; kk < 16; kk++) sum += lds[base + kk];
                gs[gt] = sum;
            }
            float iv = fast_sigmoid(gs[0]);
            float fv = fast_sigmoid(gs[1]);
            float gv = fast_tanh(gs[2]);
            float ov = fast_sigmoid(gs[3]);
            c_reg = fv * c_reg + iv * gv;
            float hv = ov * fast_tanh(c_reg);
            // plain [512][8] group buffer: word (16j+u)*8 + b = j*128 + tid
            unsigned int* hw = (unsigned int*)(hrot + (size_t)wbuf * HSLOT_WORDS
                                               + (size_t)g * H_WORDS);
            __hip_atomic_store(hw + 128 * j + tid, __float_as_uint(hv),
                               __ATOMIC_RELAXED, __HIP_MEMORY_SCOPE_AGENT);
        }
        __syncthreads();   // all h stores drained (vmcnt 0) before flag release

        if (tid == 0)
            __hip_atomic_store(myflags + j, (unsigned)(s + 1),
                               __ATOMIC_RELEASE, __HIP_MEMORY_SCOPE_AGENT);

        rbuf = wbuf;
        wbuf = (wbuf + 1 == rot_n) ? 0 : wbuf + 1;
    }
}

// FC head + softmax. h final: slot fin, group b>>3, word k*8 + (b&7).
extern "C" __global__ void __launch_bounds__(320)
lstm_epilogue(const float* __restrict__ hrot, int fin,
              const float* __restrict__ W_fc, const float* __restrict__ b_fc,
              float* __restrict__ out)
{
    __shared__ float sl[ODIM * BATCH];
    const int t = threadIdx.x;
    {
        int o = t / BATCH, b = t - o * BATCH;
        const float* hb = hrot + (size_t)fin * HSLOT_WORDS + (size_t)(b >> 3) * H_WORDS;
        const int bc = b & 7;
        float acc = b_fc[o];
        const float4* wv = (const float4*)(W_fc + o * HDIM);
#pragma unroll 8
        for (int k4 = 0; k4 < HDIM / 4; k4++) {
            float4 w = wv[k4];
            const int k0 = 4 * k4;
            acc = fmaf(hb[(k0 + 0) * 8 + bc], w.x, acc);
            acc = fmaf(hb[(k0 + 1) * 8 + bc], w.y, acc);
            acc = fmaf(hb[(k0 + 2) * 8 + bc], w.z, acc);
            acc = fmaf(hb[(k0 + 3) * 8 + bc], w.w, acc);
        }
        sl[o * BATCH + b] = acc;
    }
    __syncthreads();
    if (t < BATCH) {
        float l0 = sl[t], l1 = sl[BATCH + t], l2 = sl[2 * BATCH + t];
        float l3 = sl[3 * BATCH + t], l4 = sl[4 * BATCH + t];
        float m = fmaxf(fmaxf(fmaxf(l0, l1), fmaxf(l2, l3)), l4);
        float e0 = __expf(l0 - m), e1 = __expf(l1 - m), e2 = __expf(l2 - m);
        float e3 = __expf(l3 - m), e4 = __expf(l4 - m);
        float inv = 1.0f / (e0 + e1 + e2 + e3 + e4);
        out[t * ODIM + 0] = e0 * inv;
        out[t * ODIM + 1] = e1 * inv;
        out[t * ODIM + 2] = e2 * inv;
        out[t * ODIM + 3] = e3 * inv;
        out[t * ODIM + 4] = e4 * inv;
    }
}

extern "C" void kernel_launch(void* const* d_in, const int* in_sizes, int n_in,
                              void* d_out, int out_size, void* d_ws, size_t ws_size,
                              hipStream_t stream)
{
    const int*   x    = (const int*)d_in[0];
    const float* emb  = (const float*)d_in[1];
    const float* W_ih = (const float*)d_in[2];
    const float* W_hh = (const float*)d_in[3];
    const float* b_ih = (const float*)d_in[4];
    const float* b_hh = (const float*)d_in[5];
    const float* W_fc = (const float*)d_in[6];
    const float* b_fc = (const float*)d_in[7];
    float* out = (float*)d_out;

    // ws layout: [flags 1KB][gates (optional)][rotating h slots]
    unsigned int* flags = (unsigned int*)d_ws;
    char* p = (char*)d_ws + 1024;
    size_t remain = (ws_size > 1024) ? ws_size - 1024 : 0;
    const size_t gates_bytes = GATES_FLOATS * sizeof(float);
    float* gates = nullptr;
    if (remain >= gates_bytes + 2 * (size_t)HSLOT_BYTES) {
        gates = (float*)p;
        p += gates_bytes;
        remain -= gates_bytes;
    }
    int rot_n = (int)(remain / HSLOT_BYTES);
    if (rot_n > SEQL + 1) rot_n = SEQL + 1;
    if (rot_n < 2) rot_n = 2;
    float* hrot = (float*)p;

    (void)hipMemsetAsync(flags, 0, 1024, stream);

    (void)hipFuncSetAttribute((const void*)lstm_persist,
                              hipFuncAttributeMaxDynamicSharedMemorySize, LDS_BYTES);
    if (gates) {
        (void)hipFuncSetAttribute((const void*)lstm_pre,
                                  hipFuncAttributeMaxDynamicSharedMemorySize, PRE_LDS_BYTES);
        lstm_pre<<<SEQL * 8, 256, PRE_LDS_BYTES, stream>>>(x, emb, W_ih, gates);
    }

    lstm_persist<<<NWG, TPB, LDS_BYTES, stream>>>(x, emb, W_ih, W_hh, b_ih, b_hh,
                                                  gates, hrot, rot_n, flags);

    const int fin = SEQL % rot_n;   // slot written at step SEQL-1
    lstm_epilogue<<<1, 320, 0, stream>>>(hrot, fin, W_fc, b_fc, out);
}